// Round 16
// baseline (289.751 us; speedup 1.0000x reference)
//
#include <hip/hip_runtime.h>
#include <hip/hip_fp16.h>
#include <cstdint>
#include <cfloat>
#include <cmath>

// Problem constants
#define B_ 8
#define C_ 64
#define N_ 4096
#define O_ 64
#define K_ 20
#define EPS_ 1e-5f
#define SLOPE_ 0.2f

// knn kernel v15: BARRIER-FREE wave-streaming.
// 4 waves/block; each wave owns 16 rows (4 lanes/row) and sweeps all 64 m-tiles.
// A-frags + xx straight from global (L2/L1-hot); no LDS staging, no __syncthreads.
// Append invariant: <=64 appends/row/iter (4 lanes x 16 cols); cnt at loop start
// <= TRIG(96); CAPK = 96 + 64 = 160 -> no drops.
#define NT15 64        // m-tiles per sweep
#define CAPK15 160     // candidate buffer capacity per row
#define KEEP15 80      // compact keeps at most this many
#define TRIG15 96      // compact when cnt exceeds this
#define BSTR15 164     // buf row stride in words (164 mod 32 = 4 -> 2-way max)
#define MARGIN 0.5f    // approx-distance margin (~10 sigma of bf16-dot err + f16 quant)
#define RCAP 48        // candidates carried to exact re-rank
#define FASTN15 128    // fast compact path when wave rows all cnt <= 128 (32 regs)

typedef __attribute__((ext_vector_type(8))) short bf16x8;
typedef __attribute__((ext_vector_type(4))) float f32x4;

// workspace layout (float offsets)
#define WS_IDXB 0                 // B*N*K ints = 655360
#define WS_R1   655360            // XTf fp32 [b][n][c] = 2097152; later aliased by Pt
#define WS_R2   2752512           // region2 = 2097152 floats; later aliased by Qt (then ysel in-place)
#define R2_XTH   0                // XTh bf16 [b][n][c]: 2097152 u16 = 1048576 fl
#define R2_CANDS 1048576          // cands u16 [32768][48] = 1572864 u16 = 786432 fl
#define R2_CCNT  1835008          // 32768 ints
#define R2_XX    1867776          // 32768 floats (ends 1900544 < 2097152)
#define WS_PART 4849664           // 512*128
#define WS_SS   4915200           // 128
// end = 4915328 floats = 19.66 MB

__device__ __forceinline__ void lds_fence() {
    asm volatile("s_waitcnt lgkmcnt(0)" ::: "memory");
}
__device__ __forceinline__ unsigned short f2bf(float f) {      // RNE float->bf16
    union { float f; unsigned int u; } v; v.f = f;
    unsigned int r = v.u + 0x7FFF + ((v.u >> 16) & 1);
    return (unsigned short)(r >> 16);
}
__device__ __forceinline__ unsigned short flip16(unsigned short h) {  // order-preserving f16->u16
    return h ^ ((h & 0x8000) ? 0xFFFFu : 0x8000u);
}
__device__ __forceinline__ float val16(unsigned int k) {       // inverse of flip16, as float
    unsigned short f = (unsigned short)k;
    unsigned short orig = (f & 0x8000) ? (unsigned short)(f ^ 0x8000) : (unsigned short)(~f);
    return __half2float(__ushort_as_half(orig));
}

// Wave-private compaction: 16 rows x 4 lanes/row. Register slurp (NR regs = NR*4
// slots) -> binary-search key threshold (count>=K) -> ballot-prefix rewrite.
template<int NR>
__device__ __forceinline__ void compact4(unsigned int* buf, int* cnt, float* thrS,
                                         unsigned short* __restrict__ cands,
                                         int* __restrict__ ccnt,
                                         int wid, int lane, int b, int n0,
                                         bool emit, int iters) {
    const int row4 = (wid << 4) + (lane >> 2);           // wave-local row ownership
    const int j4 = lane & 3;
    unsigned int* br4 = &buf[row4 * BSTR15];
    int n = cnt[row4];
    if (n > NR * 4) n = NR * 4;
    unsigned int kr[NR];
    #pragma unroll
    for (int s = 0; s < NR; s++) {
        int j = 4 * s + j4;
        kr[s] = (j < n) ? br4[j] : 0u;                   // sentinel 0 never passes mid>=1
    }
    int lo = 0, hi = 65536;
    for (int itr = 0; itr < iters; ++itr) {
        int mid = (lo + hi) >> 1;
        unsigned int mk = (unsigned int)mid << 16;
        int c = 0;
        #pragma unroll
        for (int s = 0; s < NR; s++) c += (kr[s] >= mk) ? 1 : 0;
        c += __shfl_xor(c, 1);
        c += __shfl_xor(c, 2);
        if (c >= K_) lo = mid; else hi = mid;
    }
    float nthr = val16((unsigned int)lo) - MARGIN;
    unsigned int kthr = ((unsigned int)flip16(__half_as_ushort(__float2half(nthr)))) << 16;
    const size_t grow = (size_t)(b * N_ + n0 + row4);
    const int sh4 = (lane >> 2) << 2;                    // my row's nibble in the ballot
    const unsigned int lowb = (1u << j4) - 1u;
    int base = 0;
    #pragma unroll
    for (int s = 0; s < NR; s++) {                       // pass 1: core (>= lo prefix)
        int j = 4 * s + j4;
        bool p = (j < n) && ((kr[s] >> 16) >= (unsigned int)lo);
        unsigned long long bm = __ballot(p);
        unsigned int nib = (unsigned int)(bm >> sh4) & 0xFu;
        if (p) {
            int pos = base + __popc(nib & lowb);
            if (pos < KEEP15) br4[pos] = kr[s];
            if (emit && pos < RCAP) cands[grow * RCAP + pos] = (unsigned short)(kr[s] & 0xFFFu);
        }
        base += __popc(nib);
    }
    #pragma unroll
    for (int s = 0; s < NR; s++) {                       // pass 2: margin zone
        int j = 4 * s + j4;
        bool p = (j < n) && ((kr[s] >> 16) < (unsigned int)lo) && (kr[s] >= kthr);
        unsigned long long bm = __ballot(p);
        unsigned int nib = (unsigned int)(bm >> sh4) & 0xFu;
        if (p) {
            int pos = base + __popc(nib & lowb);
            if (pos < KEEP15) br4[pos] = kr[s];
            if (emit && pos < RCAP) cands[grow * RCAP + pos] = (unsigned short)(kr[s] & 0xFFFu);
        }
        base += __popc(nib);
    }
    if (j4 == 0) {
        cnt[row4] = base < KEEP15 ? base : KEEP15;
        thrS[row4] = nthr;
        if (emit) ccnt[grow] = base < RCAP ? base : RCAP;
    }
    lds_fence();
}

// ---------------------------------------------------------------- K0: transpose + bf16 + norms
__global__ __launch_bounds__(256) void k_prep(const float* __restrict__ x,
                                              float* __restrict__ XTf,
                                              unsigned short* __restrict__ XTh,
                                              float* __restrict__ xx) {
    __shared__ float xs[64][65];
    const int tid = threadIdx.x;
    const int b = blockIdx.x >> 6, n0 = (blockIdx.x & 63) << 6;
    const float* xb = x + (size_t)b * C_ * N_;
    #pragma unroll
    for (int it = 0; it < 16; it++) {
        int id = it * 256 + tid; int c = id >> 6, nl = id & 63;
        xs[c][nl] = xb[c * N_ + n0 + nl];
    }
    __syncthreads();
    #pragma unroll
    for (int it = 0; it < 4; it++) {
        int flat = it * 256 + tid; int row = flat >> 4, f4 = flat & 15;
        float v0 = xs[f4*4+0][row], v1 = xs[f4*4+1][row], v2 = xs[f4*4+2][row], v3 = xs[f4*4+3][row];
        size_t base = ((size_t)(b * N_ + n0 + row)) * 64 + f4 * 4;
        float4 fv; fv.x = v0; fv.y = v1; fv.z = v2; fv.w = v3;
        *reinterpret_cast<float4*>(XTf + base) = fv;
        ushort4 hv; hv.x = f2bf(v0); hv.y = f2bf(v1); hv.z = f2bf(v2); hv.w = f2bf(v3);
        *reinterpret_cast<ushort4*>(XTh + base) = hv;
    }
    if (tid < 64) {
        float s = 0.f;
        #pragma unroll
        for (int c = 0; c < 64; c++) { float v = xs[c][tid]; s = fmaf(v, v, s); }
        xx[b * N_ + n0 + tid] = s;
    }
}

// ---------------------------------------------------------------- K1: barrier-free wave-streaming MFMA kNN
__global__ __launch_bounds__(256, 3) void k_knn15(const unsigned short* __restrict__ XTh,
                                                  const float* __restrict__ xx,
                                                  unsigned short* __restrict__ cands,
                                                  int* __restrict__ ccnt) {
    __shared__ __align__(16) unsigned int buf[64 * BSTR15];  // per-row candidate keys (wave-private rows)
    __shared__ int   cnt[64];
    __shared__ float thrS[64];

    const int tid = threadIdx.x;
    const int wid = tid >> 6, lane = tid & 63;
    const int g = lane >> 4, lr = lane & 15;
    const int b = blockIdx.x >> 6, rb = blockIdx.x & 63;
    const int n0 = rb << 6;
    const char* Xbc = reinterpret_cast<const char*>(XTh + (size_t)b * N_ * 64);
    const float* xxb = xx + b * N_;
    const int row = (wid << 4) + lr;           // wave-owned output row (x4 lanes: g)
    unsigned int* brow = &buf[row * BSTR15];

    if (lane < 16) { cnt[(wid << 4) + lane] = 0; thrS[(wid << 4) + lane] = -3.0e38f; }
    lds_fence();                               // wave-private init, no block barrier needed

    // B fragment = own row, loaded once from global
    bf16x8 bfr[2];
    #pragma unroll
    for (int kf = 0; kf < 2; kf++)
        bfr[kf] = *reinterpret_cast<const bf16x8*>(Xbc + (size_t)(n0 + row) * 128 + kf * 64 + g * 16);
    const float cb = -xxb[n0 + row];           // -||x_n||^2

    for (int it = 0; it < NT15; ++it) {
        const int m0 = ((rb + it) & 63) << 6;
        const char* Abase = Xbc + (size_t)m0 * 128;
        const float th = thrS[row];
        // A fragments for this tile, straight from global (L1/L2-hot)
        bf16x8 af[4][2];
        #pragma unroll
        for (int rt = 0; rt < 4; rt++)
            #pragma unroll
            for (int kf = 0; kf < 2; kf++)
                af[rt][kf] = *reinterpret_cast<const bf16x8*>(Abase + (rt * 16 + lr) * 128 + kf * 64 + g * 16);
        float4 xm4[4];
        #pragma unroll
        for (int rt = 0; rt < 4; rt++)
            xm4[rt] = *reinterpret_cast<const float4*>(xxb + m0 + rt * 16 + g * 4);
        f32x4 acc[4];
        #pragma unroll
        for (int rt = 0; rt < 4; rt++) {
            acc[rt] = {0.f, 0.f, 0.f, 0.f};
            acc[rt] = __builtin_amdgcn_mfma_f32_16x16x32_bf16(af[rt][0], bfr[0], acc[rt], 0, 0, 0);
            acc[rt] = __builtin_amdgcn_mfma_f32_16x16x32_bf16(af[rt][1], bfr[1], acc[rt], 0, 0, 0);
        }
        // epilogue: nd = 2*dot - xx_n - xx_m for 16 m's of MY row
        int mask = 0;
        float4 ndq[4];
        #pragma unroll
        for (int rt = 0; rt < 4; rt++) {
            float4 xm = xm4[rt];
            float4 nv;
            nv.x = fmaf(2.f, acc[rt][0], cb) - xm.x;
            nv.y = fmaf(2.f, acc[rt][1], cb) - xm.y;
            nv.z = fmaf(2.f, acc[rt][2], cb) - xm.z;
            nv.w = fmaf(2.f, acc[rt][3], cb) - xm.w;
            ndq[rt] = nv;
            mask |= (nv.x > th ? 1 : 0) << (rt * 4);
            mask |= (nv.y > th ? 1 : 0) << (rt * 4 + 1);
            mask |= (nv.z > th ? 1 : 0) << (rt * 4 + 2);
            mask |= (nv.w > th ? 1 : 0) << (rt * 4 + 3);
        }
        // sparse ctz append (wave-private row, 4-lane contention only)
        if (mask) {
            int pos = atomicAdd(&cnt[row], __popc(mask));
            #pragma unroll
            for (int rt = 0; rt < 4; rt++) {
                int m4 = (mask >> (rt * 4)) & 15;
                float4 nv = ndq[rt];
                while (m4) {
                    int q = __builtin_ctz(m4);
                    m4 &= m4 - 1;
                    float flo = (q & 1) ? nv.y : nv.x;
                    float fhi = (q & 1) ? nv.w : nv.z;
                    float v   = (q & 2) ? fhi : flo;
                    if (pos < CAPK15) {                  // never fires under the invariant
                        int mg = m0 + rt * 16 + g * 4 + q;
                        unsigned int key = ((unsigned int)flip16(__half_as_ushort(__float2half(v))) << 16) | (unsigned int)mg;
                        brow[pos] = key;
                    }
                    pos++;
                }
            }
        }
        lds_fence();                                     // same-wave appends visible
        int myc = cnt[(wid << 4) + (lane & 15)];
        bool need = __any(myc > TRIG15);
        if (it == 0 || need) {
            int nmax = myc;                              // max over the wave's 16 rows
            nmax = max(nmax, __shfl_xor(nmax, 1));
            nmax = max(nmax, __shfl_xor(nmax, 2));
            nmax = max(nmax, __shfl_xor(nmax, 4));
            nmax = max(nmax, __shfl_xor(nmax, 8));
            if (nmax <= FASTN15) compact4<32>(buf, cnt, thrS, cands, ccnt, wid, lane, b, n0, false, 13);
            else                 compact4<40>(buf, cnt, thrS, cands, ccnt, wid, lane, b, n0, false, 13);
        }
    }
    {
        int myc = cnt[(wid << 4) + (lane & 15)];
        int nmax = myc;
        nmax = max(nmax, __shfl_xor(nmax, 1));
        nmax = max(nmax, __shfl_xor(nmax, 2));
        nmax = max(nmax, __shfl_xor(nmax, 4));
        nmax = max(nmax, __shfl_xor(nmax, 8));
        if (nmax <= FASTN15) compact4<32>(buf, cnt, thrS, cands, ccnt, wid, lane, b, n0, true, 16);
        else                 compact4<40>(buf, cnt, thrS, cands, ccnt, wid, lane, b, n0, true, 16);
    }
}

// ---------------------------------------------------------------- K2: exact fp32 re-rank of candidates -> top-20 indices
__global__ __launch_bounds__(256) void k_rerank(const float* __restrict__ XTf,
                                                const float* __restrict__ xx,
                                                const unsigned short* __restrict__ cands,
                                                const int* __restrict__ ccnt,
                                                int* __restrict__ idxb) {
    __shared__ float vals[4][RCAP];
    __shared__ int   ms[4][RCAP];
    __shared__ int   outIdx[4][K_];
    const int tid = threadIdx.x, wid = tid >> 6, lane = tid & 63;
    const size_t row = (size_t)blockIdx.x * 4 + wid;
    const int b = (int)(row >> 12), n = (int)(row & 4095);
    int cn = ccnt[row];
    cn = cn < 0 ? 0 : (cn > RCAP ? RCAP : cn);             // harden vs poison
    if (lane < K_) outIdx[wid][lane] = n;                  // hole-proof default (self)
    float nd = -FLT_MAX; int m = 0x7FFFFFFF;
    if (lane < cn) {
        m = cands[row * RCAP + lane] & 4095;
        const float* xn = XTf + ((size_t)b * N_ + n) * 64;
        const float* xm = XTf + ((size_t)b * N_ + m) * 64;
        float s = 0.f;
        #pragma unroll
        for (int i = 0; i < 16; i++) {
            float4 a  = *reinterpret_cast<const float4*>(xn + i * 4);
            float4 c2 = *reinterpret_cast<const float4*>(xm + i * 4);
            s = fmaf(a.x, c2.x, s); s = fmaf(a.y, c2.y, s);
            s = fmaf(a.z, c2.z, s); s = fmaf(a.w, c2.w, s);
        }
        nd = 2.f * s - xx[b * N_ + n] - xx[b * N_ + m];
        vals[wid][lane] = nd; ms[wid][lane] = m;
    }
    lds_fence();
    if (lane < cn) {
        int rank = 0;
        for (int j = 0; j < cn; j++) {
            float vj = vals[wid][j]; int mj = ms[wid][j];
            rank += (vj > nd) || (vj == nd && mj < m);
        }
        if (rank < K_) outIdx[wid][rank] = m;
    }
    lds_fence();
    if (lane < K_) idxb[row * K_ + lane] = outIdx[wid][lane];
}

// ---------------------------------------------------------------- K3: Pt = W1^T x, Qt = (W2-W1)^T x  (transposed [b][n][o])
__global__ __launch_bounds__(256) void k_pq(const float* __restrict__ x,
                                            const float* __restrict__ W,
                                            float* __restrict__ Pt,
                                            float* __restrict__ Qt) {
    __shared__ float2 Wl[64][65];
    __shared__ float  xT[64][64];
    const int tid = threadIdx.x;
    const int b  = blockIdx.x >> 6;
    const int n0 = (blockIdx.x & 63) * 64;
    const float* xb = x + (size_t)b * C_ * N_;

    #pragma unroll
    for (int kk = 0; kk < 16; kk++) {
        int id = tid + kk * 256;
        int c = id >> 6, o = id & 63;
        float w1 = W[o * 128 + c];
        float w2 = W[o * 128 + 64 + c];
        Wl[c][o] = make_float2(w1, w2 - w1);
    }
    #pragma unroll
    for (int kk = 0; kk < 16; kk++) {
        int id = tid + kk * 256;
        int c = id >> 6, nl = id & 63;
        xT[c][nl] = xb[c * N_ + n0 + nl];
    }
    __syncthreads();

    const int o = tid & 63, nq = tid >> 6;
    for (int s2 = 0; s2 < 4; s2++) {
        int gq = s2 * 4 + nq;
        float a1[4] = {0, 0, 0, 0}, a2[4] = {0, 0, 0, 0};
        #pragma unroll 8
        for (int c = 0; c < 64; c++) {
            float4 xv = *reinterpret_cast<const float4*>(&xT[c][gq * 4]);
            float2 wv = Wl[c][o];
            a1[0] = fmaf(wv.x, xv.x, a1[0]); a2[0] = fmaf(wv.y, xv.x, a2[0]);
            a1[1] = fmaf(wv.x, xv.y, a1[1]); a2[1] = fmaf(wv.y, xv.y, a2[1]);
            a1[2] = fmaf(wv.x, xv.z, a1[2]); a2[2] = fmaf(wv.y, xv.z, a2[2]);
            a1[3] = fmaf(wv.x, xv.w, a1[3]); a2[3] = fmaf(wv.y, xv.w, a2[3]);
        }
        #pragma unroll
        for (int gg = 0; gg < 4; gg++) {
            size_t base = ((size_t)(b * N_ + n0 + gq * 4 + gg)) * O_ + o;
            Pt[base] = a1[gg];
            Qt[base] = a2[gg];
        }
    }
}

// ---------------------------------------------------------------- K4: BN stats + gamma-directed extremum (ysel in-place into Qt)
__global__ __launch_bounds__(1024) void k_statsg(const float* __restrict__ Pt,
                                                 float* __restrict__ Qt,      // read Q, then overwrite with ysel
                                                 const int* __restrict__ idxb,
                                                 const float* __restrict__ gamma,
                                                 float* __restrict__ part) {
    const int tid = threadIdx.x;
    const int o = tid & 63, w = tid >> 6;              // w in 0..15
    const bool gsel = gamma[o] >= 0.f;                 // sc sign == gamma sign (inv>0)
    float s = 0.f, q = 0.f;
    for (int it = 0; it < 4; it++) {
        int p = blockIdx.x * 16 + w + it * 8192;       // flat (b,n)
        int b = p >> 12;
        const float* Ptb = Pt + (size_t)b * (N_ * O_);
        float Q = Qt[(size_t)p * O_ + o];
        const int* ip = idxb + (size_t)p * K_;
        float vmax = -FLT_MAX, vmin = FLT_MAX;
        #pragma unroll
        for (int k = 0; k < K_; k++) {
            int m = ip[k] & 4095;
            float v = Ptb[m * O_ + o] + Q;
            s += v;
            q = fmaf(v, v, q);
            vmax = fmaxf(vmax, v);
            vmin = fminf(vmin, v);
        }
        Qt[(size_t)p * O_ + o] = gsel ? vmax : vmin;   // in-place: this (p,o) read exactly once above
    }
    __shared__ float ps[16][64], pq2[16][64];
    ps[w][o] = s; pq2[w][o] = q;
    __syncthreads();
    if (tid < 64) {
        float S = 0.f, Qq = 0.f;
        #pragma unroll
        for (int ww = 0; ww < 16; ww++) { S += ps[ww][tid]; Qq += pq2[ww][tid]; }
        part[blockIdx.x * 128 + tid]      = S;
        part[blockIdx.x * 128 + 64 + tid] = Qq;
    }
}

// ---------------------------------------------------------------- K5: finalize mean/var -> scale/shift (parallel)
__global__ __launch_bounds__(256) void k_finalize(const float* __restrict__ part,
                                                  const float* __restrict__ gamma,
                                                  const float* __restrict__ beta,
                                                  float* __restrict__ ss) {
    __shared__ double sd[4][64], qd[4][64];
    const int o = threadIdx.x & 63, c4 = threadIdx.x >> 6;
    double s = 0.0, q = 0.0;
    for (int blk = c4 * 128; blk < (c4 + 1) * 128; blk++) {
        s += part[blk * 128 + o];
        q += part[blk * 128 + 64 + o];
    }
    sd[c4][o] = s; qd[c4][o] = q;
    __syncthreads();
    if (threadIdx.x < 64) {
        double S  = sd[0][o] + sd[1][o] + sd[2][o] + sd[3][o];
        double Qq = qd[0][o] + qd[1][o] + qd[2][o] + qd[3][o];
        double M = (double)B_ * N_ * K_;
        double mean = S / M;
        double var = Qq / M - mean * mean;
        double inv = 1.0 / sqrt(var + (double)EPS_);
        double sc = (double)gamma[o] * inv;
        ss[o]      = (float)sc;
        ss[64 + o] = (float)((double)beta[o] - mean * sc);
    }
}

// ---------------------------------------------------------------- K6: elementwise affine+leaky + transpose store
__global__ __launch_bounds__(256) void k_out2(const float* __restrict__ ysel,
                                              const float* __restrict__ ss,
                                              float* __restrict__ out) {
    __shared__ float res[64][65];
    const int tid = threadIdx.x;
    const int b  = blockIdx.x >> 6;
    const int n0 = (blockIdx.x & 63) * 64;
    const int o = tid & 63, w = tid >> 6;              // w 0..3
    const float sc = ss[o], sh = ss[64 + o];
    #pragma unroll
    for (int s2 = 0; s2 < 16; s2++) {
        int nl = s2 * 4 + w;
        float y = ysel[((size_t)(b * N_ + n0 + nl)) * O_ + o];
        float t = fmaf(y, sc, sh);
        t = t >= 0.f ? t : SLOPE_ * t;
        res[nl][o] = t;
    }
    __syncthreads();
    const int j = tid & 63, ow = tid >> 6;
    #pragma unroll
    for (int s2 = 0; s2 < 16; s2++) {
        int oo = s2 * 4 + ow;
        out[((size_t)(b * O_ + oo)) * N_ + n0 + j] = res[j][oo];
    }
}

// ---------------------------------------------------------------- launch
extern "C" void kernel_launch(void* const* d_in, const int* in_sizes, int n_in,
                              void* d_out, int out_size, void* d_ws, size_t ws_size,
                              hipStream_t stream) {
    const float* x     = (const float*)d_in[0];
    const float* W     = (const float*)d_in[1];
    const float* gamma = (const float*)d_in[2];
    const float* beta  = (const float*)d_in[3];

    float* ws = (float*)d_ws;
    int*   idxb = (int*)(ws + WS_IDXB);
    float* XTf  = ws + WS_R1;                              // aliased by Pt later
    float* R2   = ws + WS_R2;                              // aliased by Qt later (then ysel in-place)
    unsigned short* XTh   = (unsigned short*)(R2 + R2_XTH);
    unsigned short* cands = (unsigned short*)(R2 + R2_CANDS);
    int*   ccnt = (int*)(R2 + R2_CCNT);
    float* xx   = R2 + R2_XX;
    float* Pt   = ws + WS_R1;
    float* Qt   = ws + WS_R2;
    float* part = ws + WS_PART;
    float* ss   = ws + WS_SS;
    float* out  = (float*)d_out;

    hipLaunchKernelGGL(k_prep,     dim3(512),  dim3(256),  0, stream, x, XTf, XTh, xx);
    hipLaunchKernelGGL(k_knn15,    dim3(512),  dim3(256),  0, stream, XTh, xx, cands, ccnt);
    hipLaunchKernelGGL(k_rerank,   dim3(8192), dim3(256),  0, stream, XTf, xx, cands, ccnt, idxb);
    hipLaunchKernelGGL(k_pq,       dim3(512),  dim3(256),  0, stream, x, W, Pt, Qt);
    hipLaunchKernelGGL(k_statsg,   dim3(512),  dim3(1024), 0, stream, Pt, Qt, idxb, gamma, part);
    hipLaunchKernelGGL(k_finalize, dim3(1),    dim3(256),  0, stream, part, gamma, beta, ss);
    hipLaunchKernelGGL(k_out2,     dim3(512),  dim3(256),  0, stream, Qt, ss, out);
}

// Round 17
// 212.335 us; speedup vs baseline: 1.3646x; 1.3646x over previous
//
#include <hip/hip_runtime.h>
#include <hip/hip_fp16.h>
#include <cstdint>
#include <cfloat>
#include <cmath>

// Problem constants
#define B_ 8
#define C_ 64
#define N_ 4096
#define O_ 64
#define K_ 20
#define EPS_ 1e-5f
#define SLOPE_ 0.2f

// knn mfma kernel (8-wave, 64 rows/block, 2 concurrent m-groups, shared buffer)
// Append invariant: max 128 appends/row/iter (4 lanes x 16 cols x 2 groups).
// cnt at loop start <= TRIG = 96; CAPK = 96 + 128 = 224 -> no drops.
#define NT7 32         // tiles per group (2 groups x 32 x 64 cols = 4096)
#define CAPK 224       // candidate buffer capacity per row
#define KEEPCAP 80     // compact keeps at most this many (core 20 + margin zone)
#define TRIG 96        // compact when cnt exceeds this
#define BSTRIDE 228    // buf row stride in words (228 mod 32 = 4 -> 2-way max on slurp)
#define MARGIN 0.5f    // approx-distance margin (~10 sigma of bf16-dot err + f16 quant)
#define RCAP 48        // candidates carried to exact re-rank
#define FASTN 128      // fast compact path when all wave rows have cnt <= 128 (16 regs)

typedef __attribute__((ext_vector_type(8))) short bf16x8;
typedef __attribute__((ext_vector_type(4))) float f32x4;

// workspace layout (float offsets)
#define WS_IDXB 0                 // B*N*K ints = 655360
#define WS_R1   655360            // XTf fp32 [b][n][c] = 2097152; later aliased by Pt
#define WS_R2   2752512           // region2 = 2097152 floats; later aliased by Qt (then ysel in-place)
#define R2_XTH   0                // XTh bf16 [b][n][c]: 2097152 u16 = 1048576 fl
#define R2_CANDS 1048576          // cands u16 [32768][48] = 1572864 u16 = 786432 fl
#define R2_CCNT  1835008          // 32768 ints
#define R2_XX    1867776          // 32768 floats (ends 1900544 < 2097152)
#define WS_PART 4849664           // 512*128
#define WS_SS   4915200           // 128
// end = 4915328 floats = 19.66 MB

__device__ __forceinline__ void lds_fence() {
    asm volatile("s_waitcnt lgkmcnt(0)" ::: "memory");
}
__device__ __forceinline__ unsigned short f2bf(float f) {      // RNE float->bf16
    union { float f; unsigned int u; } v; v.f = f;
    unsigned int r = v.u + 0x7FFF + ((v.u >> 16) & 1);
    return (unsigned short)(r >> 16);
}
__device__ __forceinline__ unsigned short flip16(unsigned short h) {  // order-preserving f16->u16
    return h ^ ((h & 0x8000) ? 0xFFFFu : 0x8000u);
}
__device__ __forceinline__ float val16(unsigned int k) {       // inverse of flip16, as float
    unsigned short f = (unsigned short)k;
    unsigned short orig = (f & 0x8000) ? (unsigned short)(f ^ 0x8000) : (unsigned short)(~f);
    return __half2float(__ushort_as_half(orig));
}

// Race-free, atomic-free compaction: 8 waves x 8 rows each, 8 lanes/row.
// Register slurp (NR regs, covers NR*8 slots) -> binary-search key threshold
// (count>=K) -> ballot-prefix rewrite. Enforces kept <= KEEPCAP.
template<int NR>
__device__ __forceinline__ void compact_impl(unsigned int* buf, int* cnt, float* thrS,
                                             unsigned short* __restrict__ cands,
                                             int* __restrict__ ccnt,
                                             int wid, int lane, int b, int n0,
                                             bool emit, int iters) {
    const int row8 = (wid << 3) + (lane >> 3);
    const int j8 = lane & 7;
    unsigned int* br8 = &buf[row8 * BSTRIDE];
    int n = cnt[row8];
    if (n > NR * 8) n = NR * 8;                          // caller guarantees real n fits
    unsigned int kr[NR];
    #pragma unroll
    for (int s = 0; s < NR; s++) {
        int j = 8 * s + j8;
        kr[s] = (j < n) ? br8[j] : 0u;                   // sentinel 0 never passes mid>=1
    }
    int lo = 0, hi = 65536;
    for (int itr = 0; itr < iters; ++itr) {
        int mid = (lo + hi) >> 1;
        unsigned int mk = (unsigned int)mid << 16;
        int c = 0;
        #pragma unroll
        for (int s = 0; s < NR; s++) c += (kr[s] >= mk) ? 1 : 0;
        c += __shfl_xor(c, 1);
        c += __shfl_xor(c, 2);
        c += __shfl_xor(c, 4);
        if (c >= K_) lo = mid; else hi = mid;
    }
    float nthr = val16((unsigned int)lo) - MARGIN;
    unsigned int kthr = ((unsigned int)flip16(__half_as_ushort(__float2half(nthr)))) << 16;
    const size_t grow = (size_t)(b * N_ + n0 + row8);
    const int sh8 = (lane >> 3) << 3;                    // my row's byte in the 64-bit ballot
    const unsigned int lowbits = (1u << j8) - 1u;
    int base = 0;
    #pragma unroll
    for (int s = 0; s < NR; s++) {                       // pass 1: core (>= lo prefix, contains top-K)
        int j = 8 * s + j8;
        bool p = (j < n) && ((kr[s] >> 16) >= (unsigned int)lo);
        unsigned long long bm = __ballot(p);
        unsigned int byte = (unsigned int)(bm >> sh8) & 0xFFu;
        if (p) {
            int pos = base + __popc(byte & lowbits);
            if (pos < KEEPCAP) br8[pos] = kr[s];
            if (emit && pos < RCAP) cands[grow * RCAP + pos] = (unsigned short)(kr[s] & 0xFFFu);
        }
        base += __popc(byte);
    }
    #pragma unroll
    for (int s = 0; s < NR; s++) {                       // pass 2: margin zone
        int j = 8 * s + j8;
        bool p = (j < n) && ((kr[s] >> 16) < (unsigned int)lo) && (kr[s] >= kthr);
        unsigned long long bm = __ballot(p);
        unsigned int byte = (unsigned int)(bm >> sh8) & 0xFFu;
        if (p) {
            int pos = base + __popc(byte & lowbits);
            if (pos < KEEPCAP) br8[pos] = kr[s];
            if (emit && pos < RCAP) cands[grow * RCAP + pos] = (unsigned short)(kr[s] & 0xFFFu);
        }
        base += __popc(byte);
    }
    if (j8 == 0) {
        cnt[row8] = base < KEEPCAP ? base : KEEPCAP;
        thrS[row8] = nthr;
        if (emit) ccnt[grow] = base < RCAP ? base : RCAP;
    }
    lds_fence();
}

// ---------------------------------------------------------------- K0: transpose + bf16 + norms
__global__ __launch_bounds__(256) void k_prep(const float* __restrict__ x,
                                              float* __restrict__ XTf,
                                              unsigned short* __restrict__ XTh,
                                              float* __restrict__ xx) {
    __shared__ float xs[64][65];
    const int tid = threadIdx.x;
    const int b = blockIdx.x >> 6, n0 = (blockIdx.x & 63) << 6;
    const float* xb = x + (size_t)b * C_ * N_;
    #pragma unroll
    for (int it = 0; it < 16; it++) {
        int id = it * 256 + tid; int c = id >> 6, nl = id & 63;
        xs[c][nl] = xb[c * N_ + n0 + nl];
    }
    __syncthreads();
    #pragma unroll
    for (int it = 0; it < 4; it++) {
        int flat = it * 256 + tid; int row = flat >> 4, f4 = flat & 15;
        float v0 = xs[f4*4+0][row], v1 = xs[f4*4+1][row], v2 = xs[f4*4+2][row], v3 = xs[f4*4+3][row];
        size_t base = ((size_t)(b * N_ + n0 + row)) * 64 + f4 * 4;
        float4 fv; fv.x = v0; fv.y = v1; fv.z = v2; fv.w = v3;
        *reinterpret_cast<float4*>(XTf + base) = fv;
        ushort4 hv; hv.x = f2bf(v0); hv.y = f2bf(v1); hv.z = f2bf(v2); hv.w = f2bf(v3);
        *reinterpret_cast<ushort4*>(XTh + base) = hv;
    }
    if (tid < 64) {
        float s = 0.f;
        #pragma unroll
        for (int c = 0; c < 64; c++) { float v = xs[c][tid]; s = fmaf(v, v, s); }
        xx[b * N_ + n0 + tid] = s;
    }
}

// ---------------------------------------------------------------- K1: MFMA distances, 8-wave, 2 m-groups, shared buffer
__global__ __launch_bounds__(512, 4) void k_knn14(const unsigned short* __restrict__ XTh,
                                                  const float* __restrict__ xx,
                                                  unsigned short* __restrict__ cands,
                                                  int* __restrict__ ccnt) {
    __shared__ __align__(16) unsigned short Bt[2][4096];     // [group] 64x64 bf16, XOR-swizzled
    __shared__ __align__(16) float xxc[2][64];
    __shared__ __align__(16) unsigned int buf[64 * BSTRIDE]; // shared per-row candidate keys
    __shared__ int   cnt[64];
    __shared__ float thrS[64];

    const int tid = threadIdx.x;
    const int wid = tid >> 6, lane = tid & 63;
    const int gid = wid >> 2;                  // m-group (0/1)
    const int vw  = wid & 3;                   // wave within group
    const int g = lane >> 4, lr = lane & 15;
    const int gtid = (vw << 6) + lane;         // 0..255 within group
    const int b = blockIdx.x >> 6, rb = blockIdx.x & 63;
    const int n0 = rb << 6;
    const unsigned short* Xb = XTh + (size_t)b * N_ * 64;
    const float* xxb = xx + b * N_;
    const int row = (vw << 4) + lr;            // own output row (x4 lanes x2 groups)
    unsigned int* brow = &buf[row * BSTRIDE];

    // stage own 64 rows into buf-head area (swizzled); each group stages its first m-tile
    unsigned short* rows = reinterpret_cast<unsigned short*>(buf);
    {
        uint4 gv = *reinterpret_cast<const uint4*>(reinterpret_cast<const char*>(Xb) + (size_t)n0 * 128 + (size_t)tid * 16);
        int r = tid >> 3, cc = tid & 7;
        *reinterpret_cast<uint4*>(reinterpret_cast<char*>(rows) + r * 128 + ((cc * 16) ^ ((r & 7) << 4))) = gv;
    }
    {
        const int m0 = ((rb + (gid << 5)) & 63) << 6;        // group0 starts at self tile
        #pragma unroll
        for (int it2 = 0; it2 < 2; it2++) {
            int u = it2 * 256 + gtid;
            uint4 gv = *reinterpret_cast<const uint4*>(reinterpret_cast<const char*>(Xb) + (size_t)m0 * 128 + (size_t)u * 16);
            int r = u >> 3, cc = u & 7;
            *reinterpret_cast<uint4*>(reinterpret_cast<char*>(Bt[gid]) + r * 128 + ((cc * 16) ^ ((r & 7) << 4))) = gv;
        }
        if (gtid < 64) xxc[gid][gtid] = xxb[m0 + gtid];
    }
    if (tid < 64) { cnt[tid] = 0; thrS[tid] = -3.0e38f; }
    __syncthreads();

    // B fragment = own row, register-resident for the whole sweep
    bf16x8 bfr[2];
    #pragma unroll
    for (int kf = 0; kf < 2; kf++)
        bfr[kf] = *reinterpret_cast<const bf16x8*>(reinterpret_cast<const char*>(rows) + row * 128 + ((((kf << 6)) + (g << 4)) ^ ((row & 7) << 4)));
    const float cb = -xxb[n0 + row];           // -||x_n||^2
    __syncthreads();                           // all frag reads done before buf reuse

    // hoisted loop-invariant LDS pointers (single-buffered Bt -> constant all sweep)
    const char* afp[4][2];
    #pragma unroll
    for (int rt = 0; rt < 4; rt++)
        #pragma unroll
        for (int kf = 0; kf < 2; kf++) {
            int r = rt * 16 + lr;
            afp[rt][kf] = reinterpret_cast<const char*>(Bt[gid]) + r * 128 + ((((kf << 6)) + (g << 4)) ^ ((r & 7) << 4));
        }
    const float* xxp[4];
    #pragma unroll
    for (int rt = 0; rt < 4; rt++) xxp[rt] = &xxc[gid][rt * 16 + g * 4];

    for (int it = 0; it < NT7; ++it) {
        const int m0 = ((rb + (gid << 5) + it) & 63) << 6;
        // prefetch next tile for this group into registers (consumed after the barrier)
        uint4 g0, g1; float xcn = 0.f;
        if (it + 1 < NT7) {
            const int m0n = ((rb + (gid << 5) + it + 1) & 63) << 6;
            g0 = *reinterpret_cast<const uint4*>(reinterpret_cast<const char*>(Xb) + (size_t)m0n * 128 + (size_t)gtid * 16);
            g1 = *reinterpret_cast<const uint4*>(reinterpret_cast<const char*>(Xb) + (size_t)m0n * 128 + (size_t)(256 + gtid) * 16);
            if (gtid < 64) xcn = xxb[m0n + gtid];
        }
        const float th = thrS[row];
        // A fragments (this group's streamed m-tile), hoisted addresses
        bf16x8 af[4][2];
        #pragma unroll
        for (int rt = 0; rt < 4; rt++)
            #pragma unroll
            for (int kf = 0; kf < 2; kf++)
                af[rt][kf] = *reinterpret_cast<const bf16x8*>(afp[rt][kf]);
        f32x4 acc[4];
        #pragma unroll
        for (int rt = 0; rt < 4; rt++) {
            acc[rt] = {0.f, 0.f, 0.f, 0.f};
            acc[rt] = __builtin_amdgcn_mfma_f32_16x16x32_bf16(af[rt][0], bfr[0], acc[rt], 0, 0, 0);
            acc[rt] = __builtin_amdgcn_mfma_f32_16x16x32_bf16(af[rt][1], bfr[1], acc[rt], 0, 0, 0);
        }
        // epilogue: nd = 2*dot - xx_n - xx_m for 16 m's of MY row
        int mask = 0;
        float4 ndq[4];
        #pragma unroll
        for (int rt = 0; rt < 4; rt++) {
            float4 xm = *reinterpret_cast<const float4*>(xxp[rt]);
            float4 nv;
            nv.x = fmaf(2.f, acc[rt][0], cb) - xm.x;
            nv.y = fmaf(2.f, acc[rt][1], cb) - xm.y;
            nv.z = fmaf(2.f, acc[rt][2], cb) - xm.z;
            nv.w = fmaf(2.f, acc[rt][3], cb) - xm.w;
            ndq[rt] = nv;
            mask |= (nv.x > th ? 1 : 0) << (rt * 4);
            mask |= (nv.y > th ? 1 : 0) << (rt * 4 + 1);
            mask |= (nv.z > th ? 1 : 0) << (rt * 4 + 2);
            mask |= (nv.w > th ? 1 : 0) << (rt * 4 + 3);
        }
        // sparse append: iterate only over SET bits (ctz loop) -- issued work
        // scales with actual appends (~1-2/lane/iter), not the 16-slot unroll.
        if (mask) {
            int pos = atomicAdd(&cnt[row], __popc(mask));
            #pragma unroll
            for (int rt = 0; rt < 4; rt++) {
                int m4 = (mask >> (rt * 4)) & 15;
                float4 nv = ndq[rt];
                while (m4) {
                    int q = __builtin_ctz(m4);
                    m4 &= m4 - 1;
                    float flo = (q & 1) ? nv.y : nv.x;      // static components, cndmask select
                    float fhi = (q & 1) ? nv.w : nv.z;
                    float v   = (q & 2) ? fhi : flo;
                    if (pos < CAPK) {                        // never fires under the invariant
                        int mg = m0 + rt * 16 + g * 4 + q;
                        unsigned int key = ((unsigned int)flip16(__half_as_ushort(__float2half(v))) << 16) | (unsigned int)mg;
                        brow[pos] = key;
                    }
                    pos++;
                }
            }
        }
        __syncthreads();                                     // Bt readers done + appends visible
        // stage prefetched tile (single buffer, safe after barrier)
        if (it + 1 < NT7) {
            { int r = gtid >> 3, cc = gtid & 7;
              *reinterpret_cast<uint4*>(reinterpret_cast<char*>(Bt[gid]) + r * 128 + ((cc * 16) ^ ((r & 7) << 4))) = g0; }
            { int u = 256 + gtid; int r = u >> 3, cc = u & 7;
              *reinterpret_cast<uint4*>(reinterpret_cast<char*>(Bt[gid]) + r * 128 + ((cc * 16) ^ ((r & 7) << 4))) = g1; }
            if (gtid < 64) xxc[gid][gtid] = xcn;
        }
        bool need = __any(cnt[lane] > TRIG);                 // uniform across waves (post-barrier)
        if (need) {
            int nmax = cnt[(wid << 3) + (lane >> 3)];        // wave-uniform fast-path select
            nmax = max(nmax, __shfl_xor(nmax, 8));
            nmax = max(nmax, __shfl_xor(nmax, 16));
            nmax = max(nmax, __shfl_xor(nmax, 32));
            if (nmax <= FASTN) compact_impl<16>(buf, cnt, thrS, cands, ccnt, wid, lane, b, n0, false, 13);
            else               compact_impl<28>(buf, cnt, thrS, cands, ccnt, wid, lane, b, n0, false, 13);
        }
        __syncthreads();                                     // staging + compact visible
    }
    {
        int nmax = cnt[(wid << 3) + (lane >> 3)];
        nmax = max(nmax, __shfl_xor(nmax, 8));
        nmax = max(nmax, __shfl_xor(nmax, 16));
        nmax = max(nmax, __shfl_xor(nmax, 32));
        if (nmax <= FASTN) compact_impl<16>(buf, cnt, thrS, cands, ccnt, wid, lane, b, n0, true, 16);
        else               compact_impl<28>(buf, cnt, thrS, cands, ccnt, wid, lane, b, n0, true, 16);
    }
}

// ---------------------------------------------------------------- K2: exact fp32 re-rank of candidates -> top-20 indices
__global__ __launch_bounds__(256) void k_rerank(const float* __restrict__ XTf,
                                                const float* __restrict__ xx,
                                                const unsigned short* __restrict__ cands,
                                                const int* __restrict__ ccnt,
                                                int* __restrict__ idxb) {
    __shared__ float vals[4][RCAP];
    __shared__ int   ms[4][RCAP];
    __shared__ int   outIdx[4][K_];
    const int tid = threadIdx.x, wid = tid >> 6, lane = tid & 63;
    const size_t row = (size_t)blockIdx.x * 4 + wid;
    const int b = (int)(row >> 12), n = (int)(row & 4095);
    int cn = ccnt[row];
    cn = cn < 0 ? 0 : (cn > RCAP ? RCAP : cn);             // harden vs poison
    if (lane < K_) outIdx[wid][lane] = n;                  // hole-proof default (self)
    float nd = -FLT_MAX; int m = 0x7FFFFFFF;
    if (lane < cn) {
        m = cands[row * RCAP + lane] & 4095;
        const float* xn = XTf + ((size_t)b * N_ + n) * 64;
        const float* xm = XTf + ((size_t)b * N_ + m) * 64;
        float s = 0.f;
        #pragma unroll
        for (int i = 0; i < 16; i++) {
            float4 a  = *reinterpret_cast<const float4*>(xn + i * 4);
            float4 c2 = *reinterpret_cast<const float4*>(xm + i * 4);
            s = fmaf(a.x, c2.x, s); s = fmaf(a.y, c2.y, s);
            s = fmaf(a.z, c2.z, s); s = fmaf(a.w, c2.w, s);
        }
        nd = 2.f * s - xx[b * N_ + n] - xx[b * N_ + m];
        vals[wid][lane] = nd; ms[wid][lane] = m;
    }
    lds_fence();
    if (lane < cn) {
        int rank = 0;
        for (int j = 0; j < cn; j++) {
            float vj = vals[wid][j]; int mj = ms[wid][j];
            rank += (vj > nd) || (vj == nd && mj < m);
        }
        if (rank < K_) outIdx[wid][rank] = m;
    }
    lds_fence();
    if (lane < K_) idxb[row * K_ + lane] = outIdx[wid][lane];
}

// ---------------------------------------------------------------- K3: Pt = W1^T x, Qt = (W2-W1)^T x  (transposed [b][n][o])
__global__ __launch_bounds__(256) void k_pq(const float* __restrict__ x,
                                            const float* __restrict__ W,
                                            float* __restrict__ Pt,
                                            float* __restrict__ Qt) {
    __shared__ float2 Wl[64][65];
    __shared__ float  xT[64][64];
    const int tid = threadIdx.x;
    const int b  = blockIdx.x >> 6;
    const int n0 = (blockIdx.x & 63) * 64;
    const float* xb = x + (size_t)b * C_ * N_;

    #pragma unroll
    for (int kk = 0; kk < 16; kk++) {
        int id = tid + kk * 256;
        int c = id >> 6, o = id & 63;
        float w1 = W[o * 128 + c];
        float w2 = W[o * 128 + 64 + c];
        Wl[c][o] = make_float2(w1, w2 - w1);
    }
    #pragma unroll
    for (int kk = 0; kk < 16; kk++) {
        int id = tid + kk * 256;
        int c = id >> 6, nl = id & 63;
        xT[c][nl] = xb[c * N_ + n0 + nl];
    }
    __syncthreads();

    const int o = tid & 63, nq = tid >> 6;
    for (int s2 = 0; s2 < 4; s2++) {
        int gq = s2 * 4 + nq;
        float a1[4] = {0, 0, 0, 0}, a2[4] = {0, 0, 0, 0};
        #pragma unroll 8
        for (int c = 0; c < 64; c++) {
            float4 xv = *reinterpret_cast<const float4*>(&xT[c][gq * 4]);
            float2 wv = Wl[c][o];
            a1[0] = fmaf(wv.x, xv.x, a1[0]); a2[0] = fmaf(wv.y, xv.x, a2[0]);
            a1[1] = fmaf(wv.x, xv.y, a1[1]); a2[1] = fmaf(wv.y, xv.y, a2[1]);
            a1[2] = fmaf(wv.x, xv.z, a1[2]); a2[2] = fmaf(wv.y, xv.z, a2[2]);
            a1[3] = fmaf(wv.x, xv.w, a1[3]); a2[3] = fmaf(wv.y, xv.w, a2[3]);
        }
        #pragma unroll
        for (int gg = 0; gg < 4; gg++) {
            size_t base = ((size_t)(b * N_ + n0 + gq * 4 + gg)) * O_ + o;
            Pt[base] = a1[gg];
            Qt[base] = a2[gg];
        }
    }
}

// ---------------------------------------------------------------- K4: BN stats + gamma-directed extremum (ysel in-place into Qt)
__global__ __launch_bounds__(1024) void k_statsg(const float* __restrict__ Pt,
                                                 float* __restrict__ Qt,      // read Q, then overwrite with ysel
                                                 const int* __restrict__ idxb,
                                                 const float* __restrict__ gamma,
                                                 float* __restrict__ part) {
    const int tid = threadIdx.x;
    const int o = tid & 63, w = tid >> 6;              // w in 0..15
    const bool gsel = gamma[o] >= 0.f;                 // sc sign == gamma sign (inv>0)
    float s = 0.f, q = 0.f;
    for (int it = 0; it < 4; it++) {
        int p = blockIdx.x * 16 + w + it * 8192;       // flat (b,n)
        int b = p >> 12;
        const float* Ptb = Pt + (size_t)b * (N_ * O_);
        float Q = Qt[(size_t)p * O_ + o];
        const int* ip = idxb + (size_t)p * K_;
        float vmax = -FLT_MAX, vmin = FLT_MAX;
        #pragma unroll
        for (int k = 0; k < K_; k++) {
            int m = ip[k] & 4095;
            float v = Ptb[m * O_ + o] + Q;
            s += v;
            q = fmaf(v, v, q);
            vmax = fmaxf(vmax, v);
            vmin = fminf(vmin, v);
        }
        Qt[(size_t)p * O_ + o] = gsel ? vmax : vmin;   // in-place: this (p,o) read exactly once above
    }
    __shared__ float ps[16][64], pq2[16][64];
    ps[w][o] = s; pq2[w][o] = q;
    __syncthreads();
    if (tid < 64) {
        float S = 0.f, Qq = 0.f;
        #pragma unroll
        for (int ww = 0; ww < 16; ww++) { S += ps[ww][tid]; Qq += pq2[ww][tid]; }
        part[blockIdx.x * 128 + tid]      = S;
        part[blockIdx.x * 128 + 64 + tid] = Qq;
    }
}

// ---------------------------------------------------------------- K5: finalize mean/var -> scale/shift (parallel)
__global__ __launch_bounds__(256) void k_finalize(const float* __restrict__ part,
                                                  const float* __restrict__ gamma,
                                                  const float* __restrict__ beta,
                                                  float* __restrict__ ss) {
    __shared__ double sd[4][64], qd[4][64];
    const int o = threadIdx.x & 63, c4 = threadIdx.x >> 6;
    double s = 0.0, q = 0.0;
    for (int blk = c4 * 128; blk < (c4 + 1) * 128; blk++) {
        s += part[blk * 128 + o];
        q += part[blk * 128 + 64 + o];
    }
    sd[c4][o] = s; qd[c4][o] = q;
    __syncthreads();
    if (threadIdx.x < 64) {
        double S  = sd[0][o] + sd[1][o] + sd[2][o] + sd[3][o];
        double Qq = qd[0][o] + qd[1][o] + qd[2][o] + qd[3][o];
        double M = (double)B_ * N_ * K_;
        double mean = S / M;
        double var = Qq / M - mean * mean;
        double inv = 1.0 / sqrt(var + (double)EPS_);
        double sc = (double)gamma[o] * inv;
        ss[o]      = (float)sc;
        ss[64 + o] = (float)((double)beta[o] - mean * sc);
    }
}

// ---------------------------------------------------------------- K6: elementwise affine+leaky + transpose store
__global__ __launch_bounds__(256) void k_out2(const float* __restrict__ ysel,
                                              const float* __restrict__ ss,
                                              float* __restrict__ out) {
    __shared__ float res[64][65];
    const int tid = threadIdx.x;
    const int b  = blockIdx.x >> 6;
    const int n0 = (blockIdx.x & 63) * 64;
    const int o = tid & 63, w = tid >> 6;              // w 0..3
    const float sc = ss[o], sh = ss[64 + o];
    #pragma unroll
    for (int s2 = 0; s2 < 16; s2++) {
        int nl = s2 * 4 + w;
        float y = ysel[((size_t)(b * N_ + n0 + nl)) * O_ + o];
        float t = fmaf(y, sc, sh);
        t = t >= 0.f ? t : SLOPE_ * t;
        res[nl][o] = t;
    }
    __syncthreads();
    const int j = tid & 63, ow = tid >> 6;
    #pragma unroll
    for (int s2 = 0; s2 < 16; s2++) {
        int oo = s2 * 4 + ow;
        out[((size_t)(b * O_ + oo)) * N_ + n0 + j] = res[j][oo];
    }
}

// ---------------------------------------------------------------- launch
extern "C" void kernel_launch(void* const* d_in, const int* in_sizes, int n_in,
                              void* d_out, int out_size, void* d_ws, size_t ws_size,
                              hipStream_t stream) {
    const float* x     = (const float*)d_in[0];
    const float* W     = (const float*)d_in[1];
    const float* gamma = (const float*)d_in[2];
    const float* beta  = (const float*)d_in[3];

    float* ws = (float*)d_ws;
    int*   idxb = (int*)(ws + WS_IDXB);
    float* XTf  = ws + WS_R1;                              // aliased by Pt later
    float* R2   = ws + WS_R2;                              // aliased by Qt later (then ysel in-place)
    unsigned short* XTh   = (unsigned short*)(R2 + R2_XTH);
    unsigned short* cands = (unsigned short*)(R2 + R2_CANDS);
    int*   ccnt = (int*)(R2 + R2_CCNT);
    float* xx   = R2 + R2_XX;
    float* Pt   = ws + WS_R1;
    float* Qt   = ws + WS_R2;
    float* part = ws + WS_PART;
    float* ss   = ws + WS_SS;
    float* out  = (float*)d_out;

    hipLaunchKernelGGL(k_prep,     dim3(512),  dim3(256),  0, stream, x, XTf, XTh, xx);
    hipLaunchKernelGGL(k_knn14,    dim3(512),  dim3(512),  0, stream, XTh, xx, cands, ccnt);
    hipLaunchKernelGGL(k_rerank,   dim3(8192), dim3(256),  0, stream, XTf, xx, cands, ccnt, idxb);
    hipLaunchKernelGGL(k_pq,       dim3(512),  dim3(256),  0, stream, x, W, Pt, Qt);
    hipLaunchKernelGGL(k_statsg,   dim3(512),  dim3(1024), 0, stream, Pt, Qt, idxb, gamma, part);
    hipLaunchKernelGGL(k_finalize, dim3(1),    dim3(256),  0, stream, part, gamma, beta, ss);
    hipLaunchKernelGGL(k_out2,     dim3(512),  dim3(256),  0, stream, Qt, ss, out);
}